// Round 1
// baseline (624.614 us; speedup 1.0000x reference)
//
#include <hip/hip_runtime.h>
#include <hip/hip_bf16.h>
#include <math.h>

#define NTOK 8192
#define HD 1024
#define ID 4096
#define NE 8

typedef __attribute__((ext_vector_type(8))) short short8;
typedef __attribute__((ext_vector_type(4))) float floatx4;

__device__ __forceinline__ unsigned short f2bf(float f) {
  unsigned int u = __float_as_uint(f);
  return (unsigned short)((u + 0x7fffu + ((u >> 16) & 1u)) >> 16);
}

__device__ __forceinline__ void async_ld16(const void* g, void* l) {
  __builtin_amdgcn_global_load_lds(
      (const __attribute__((address_space(1))) unsigned int*)g,
      (__attribute__((address_space(3))) unsigned int*)l,
      16, 0, 0);
}

// ---------------- small kernels ----------------

__global__ void zero_counts_kernel(int* __restrict__ cnts) {
  if (threadIdx.x < 16) cnts[threadIdx.x] = 0;  // counts[8] + cursors[8]
}

__global__ void cast_x_kernel(const float* __restrict__ x, unsigned short* __restrict__ xb) {
  int i = (blockIdx.x * 256 + threadIdx.x) * 4;
  float4 v = *(const float4*)(x + i);
  ushort4 o;
  o.x = f2bf(v.x); o.y = f2bf(v.y); o.z = f2bf(v.z); o.w = f2bf(v.w);
  *(ushort4*)(xb + i) = o;
}

// src: batch of [R][C] fp32, dst: batch of [C][R] bf16
__global__ void transpose_cast_kernel(const float* __restrict__ src,
                                      unsigned short* __restrict__ dst, int R, int C) {
  size_t bo = (size_t)blockIdx.z * R * C;
  src += bo; dst += bo;
  __shared__ float t[32][33];
  int c0 = blockIdx.x * 32, r0 = blockIdx.y * 32;
  int tx = threadIdx.x & 31, ty = threadIdx.x >> 5;
#pragma unroll
  for (int q = 0; q < 4; q++) {
    int r = ty + q * 8;
    t[r][tx] = src[(size_t)(r0 + r) * C + c0 + tx];
  }
  __syncthreads();
#pragma unroll
  for (int q = 0; q < 4; q++) {
    int cc = ty + q * 8;
    dst[(size_t)(c0 + cc) * R + r0 + tx] = f2bf(t[tx][cc]);
  }
}

// fp64-accumulated router logits + argmax (must match reference routing exactly)
__global__ void router_kernel(const float* __restrict__ x, const float* __restrict__ wr,
                              int* __restrict__ eidx, int* __restrict__ counts) {
  int wave = threadIdx.x >> 6, lane = threadIdx.x & 63;
  int n = blockIdx.x * 4 + wave;
  const float* xr = x + (size_t)n * HD;
  double acc[NE];
#pragma unroll
  for (int e = 0; e < NE; e++) acc[e] = 0.0;
#pragma unroll
  for (int v = 0; v < 4; v++) {
    int h = (lane + v * 64) * 4;
    float4 xv = *(const float4*)(xr + h);
#pragma unroll
    for (int e = 0; e < NE; e++) {
      float4 wv = *(const float4*)(wr + e * HD + h);
      acc[e] += (double)xv.x * wv.x + (double)xv.y * wv.y +
                (double)xv.z * wv.z + (double)xv.w * wv.w;
    }
  }
#pragma unroll
  for (int m = 32; m >= 1; m >>= 1) {
#pragma unroll
    for (int e = 0; e < NE; e++) acc[e] += __shfl_xor(acc[e], m, 64);
  }
  if (lane == 0) {
    int best = 0; double bv = acc[0];
#pragma unroll
    for (int e = 1; e < NE; e++) if (acc[e] > bv) { bv = acc[e]; best = e; }
    eidx[n] = best;
    atomicAdd(&counts[best], 1);
  }
}

__global__ void scan_kernel(const int* __restrict__ counts, int* __restrict__ offs) {
  if (threadIdx.x == 0) {
    int s = 0;
    for (int e = 0; e < NE; e++) { offs[e] = s; s += counts[e]; }
    offs[NE] = s;
  }
}

__global__ void scatter_kernel(const int* __restrict__ eidx, const int* __restrict__ offs,
                               int* __restrict__ cursors, int* __restrict__ perm) {
  int n = blockIdx.x * 256 + threadIdx.x;
  int e = eidx[n];
  int pos = offs[e] + atomicAdd(&cursors[e], 1);
  perm[pos] = n;
}

// ---------------- GEMM kernels ----------------
// 128x128 tile, BK=64, 4 waves (2x2), 4x4 MFMA frags/wave, 16x16x32 bf16.
// LDS layout: [row][64] bf16, 16B chunks XOR-swizzled by (row&7) so both
// global_load_lds staging (lane*16 contiguous) and ds_read_b128 frag reads
// are conflict-free.

__global__ __launch_bounds__(256, 2) void ffn1_kernel(
    const unsigned short* __restrict__ xb, const unsigned short* __restrict__ w1t,
    const float* __restrict__ b1, const int* __restrict__ perm,
    const int* __restrict__ offs, const int* __restrict__ counts,
    unsigned short* __restrict__ interb) {
  int e = blockIdx.z;
  int cnt = counts[e];
  int tm = blockIdx.y;
  if (tm * 128 >= cnt) return;
  int nb = blockIdx.x * 128;
  int off_e = offs[e];

  __shared__ unsigned short lA[128 * 64];
  __shared__ unsigned short lB[128 * 64];

  int tid = threadIdx.x;
  int wave = tid >> 6, lane = tid & 63;
  int lr = lane >> 3;              // row-within-8-row-chunk
  int chunk = (lane & 7) ^ lr;     // swizzled 16B chunk selector

  const unsigned short* gA[4];
  const unsigned short* gB[4];
#pragma unroll
  for (int q = 0; q < 4; q++) {
    int c = wave * 4 + q;
    int tr = tm * 128 + c * 8 + lr;
    int rr = off_e + (tr < cnt ? tr : cnt - 1);  // clamp tail rows (stores masked)
    int token = perm[rr];
    gA[q] = xb + (size_t)token * HD + chunk * 8;
    int nr = nb + c * 8 + lr;
    gB[q] = w1t + ((size_t)e * ID + nr) * HD + chunk * 8;
  }

  floatx4 acc[4][4];
#pragma unroll
  for (int i = 0; i < 4; i++)
#pragma unroll
    for (int j = 0; j < 4; j++) acc[i][j] = (floatx4){0.f, 0.f, 0.f, 0.f};

  int wm = (wave >> 1) * 64, wn = (wave & 1) * 64;
  int c15 = lane & 15, q4 = lane >> 4;

  for (int ko = 0; ko < HD / 64; ko++) {
#pragma unroll
    for (int q = 0; q < 4; q++) {
      int c = wave * 4 + q;
      async_ld16(gA[q] + ko * 64, &lA[c * 512]);
      async_ld16(gB[q] + ko * 64, &lB[c * 512]);
    }
    __syncthreads();
#pragma unroll
    for (int kk = 0; kk < 2; kk++) {
      short8 af[4], bfr[4];
#pragma unroll
      for (int i = 0; i < 4; i++) {
        int m = wm + i * 16 + c15;
        int sa = (kk * 4 + q4) ^ (m & 7);
        af[i] = *(const short8*)&lA[m * 64 + sa * 8];
        int n = wn + i * 16 + c15;
        int sb = (kk * 4 + q4) ^ (n & 7);
        bfr[i] = *(const short8*)&lB[n * 64 + sb * 8];
      }
#pragma unroll
      for (int i = 0; i < 4; i++)
#pragma unroll
        for (int j = 0; j < 4; j++)
          acc[i][j] = __builtin_amdgcn_mfma_f32_16x16x32_bf16(af[i], bfr[j], acc[i][j], 0, 0, 0);
    }
    __syncthreads();
  }

#pragma unroll
  for (int i = 0; i < 4; i++) {
#pragma unroll
    for (int r = 0; r < 4; r++) {
      int tr = tm * 128 + wm + i * 16 + q4 * 4 + r;
      if (tr >= cnt) continue;
      int token = perm[off_e + tr];
#pragma unroll
      for (int j = 0; j < 4; j++) {
        int col = nb + wn + j * 16 + c15;
        float v = acc[i][j][r] + b1[e * ID + col];
        v = 0.5f * v * (1.0f + erff(v * 0.70710678118654752f));  // exact GELU
        interb[(size_t)token * ID + col] = f2bf(v);
      }
    }
  }
}

__global__ __launch_bounds__(256, 2) void ffn2_kernel(
    const unsigned short* __restrict__ interb, const unsigned short* __restrict__ wot,
    const float* __restrict__ bo, const float* __restrict__ x, float* __restrict__ y) {
  int tm = blockIdx.y;
  int nb = blockIdx.x * 128;

  __shared__ unsigned short lA[128 * 64];
  __shared__ unsigned short lB[128 * 64];

  int tid = threadIdx.x;
  int wave = tid >> 6, lane = tid & 63;
  int lr = lane >> 3;
  int chunk = (lane & 7) ^ lr;

  const unsigned short* gA[4];
  const unsigned short* gB[4];
#pragma unroll
  for (int q = 0; q < 4; q++) {
    int c = wave * 4 + q;
    int row = tm * 128 + c * 8 + lr;
    gA[q] = interb + (size_t)row * ID + chunk * 8;
    int nr = nb + c * 8 + lr;
    gB[q] = wot + (size_t)nr * ID + chunk * 8;
  }

  floatx4 acc[4][4];
#pragma unroll
  for (int i = 0; i < 4; i++)
#pragma unroll
    for (int j = 0; j < 4; j++) acc[i][j] = (floatx4){0.f, 0.f, 0.f, 0.f};

  int wm = (wave >> 1) * 64, wn = (wave & 1) * 64;
  int c15 = lane & 15, q4 = lane >> 4;

  for (int ko = 0; ko < ID / 64; ko++) {
#pragma unroll
    for (int q = 0; q < 4; q++) {
      int c = wave * 4 + q;
      async_ld16(gA[q] + ko * 64, &lA[c * 512]);
      async_ld16(gB[q] + ko * 64, &lB[c * 512]);
    }
    __syncthreads();
#pragma unroll
    for (int kk = 0; kk < 2; kk++) {
      short8 af[4], bfr[4];
#pragma unroll
      for (int i = 0; i < 4; i++) {
        int m = wm + i * 16 + c15;
        int sa = (kk * 4 + q4) ^ (m & 7);
        af[i] = *(const short8*)&lA[m * 64 + sa * 8];
        int n = wn + i * 16 + c15;
        int sb = (kk * 4 + q4) ^ (n & 7);
        bfr[i] = *(const short8*)&lB[n * 64 + sb * 8];
      }
#pragma unroll
      for (int i = 0; i < 4; i++)
#pragma unroll
        for (int j = 0; j < 4; j++)
          acc[i][j] = __builtin_amdgcn_mfma_f32_16x16x32_bf16(af[i], bfr[j], acc[i][j], 0, 0, 0);
    }
    __syncthreads();
  }

#pragma unroll
  for (int i = 0; i < 4; i++) {
#pragma unroll
    for (int r = 0; r < 4; r++) {
      int row = tm * 128 + wm + i * 16 + q4 * 4 + r;
#pragma unroll
      for (int j = 0; j < 4; j++) {
        int col = nb + wn + j * 16 + c15;
        float v = acc[i][j][r] + bo[col] + x[(size_t)row * HD + col];
        y[(size_t)row * HD + col] = v;  // pre-LN y staged in d_out
      }
    }
  }
}

__global__ void ln_kernel(float* __restrict__ y, const float* __restrict__ gamma,
                          const float* __restrict__ beta) {
  int row = blockIdx.x, t = threadIdx.x;
  int lane = t & 63, wave = t >> 6;
  float* yr = y + (size_t)row * HD;
  float4 v = *(const float4*)(yr + t * 4);
  float s = v.x + v.y + v.z + v.w;
  float ss = v.x * v.x + v.y * v.y + v.z * v.z + v.w * v.w;
#pragma unroll
  for (int m = 32; m >= 1; m >>= 1) {
    s += __shfl_xor(s, m, 64);
    ss += __shfl_xor(ss, m, 64);
  }
  __shared__ float sred[4], ssred[4];
  if (lane == 0) { sred[wave] = s; ssred[wave] = ss; }
  __syncthreads();
  s = sred[0] + sred[1] + sred[2] + sred[3];
  ss = ssred[0] + ssred[1] + ssred[2] + ssred[3];
  float mu = s * (1.0f / HD);
  float var = ss * (1.0f / HD) - mu * mu;
  float rs = rsqrtf(var + 1e-12f);
  float4 g = *(const float4*)(gamma + t * 4);
  float4 b = *(const float4*)(beta + t * 4);
  float4 o;
  o.x = (v.x - mu) * rs * g.x + b.x;
  o.y = (v.y - mu) * rs * g.y + b.y;
  o.z = (v.z - mu) * rs * g.z + b.z;
  o.w = (v.w - mu) * rs * g.w + b.w;
  *(float4*)(yr + t * 4) = o;
}

// ---------------- host launcher ----------------

extern "C" void kernel_launch(void* const* d_in, const int* in_sizes, int n_in,
                              void* d_out, int out_size, void* d_ws, size_t ws_size,
                              hipStream_t stream) {
  const float* x     = (const float*)d_in[0];
  const float* wr    = (const float*)d_in[1];
  const float* w1    = (const float*)d_in[2];
  const float* b1    = (const float*)d_in[3];
  const float* wo    = (const float*)d_in[4];
  const float* bo    = (const float*)d_in[5];
  const float* gamma = (const float*)d_in[6];
  const float* beta  = (const float*)d_in[7];
  float* out = (float*)d_out;

  char* p = (char*)d_ws;
  unsigned short* w1t = (unsigned short*)p; p += (size_t)NE * ID * HD * 2;   // 67 MB
  unsigned short* wot = (unsigned short*)p; p += (size_t)HD * ID * 2;        // 8.4 MB
  unsigned short* xb  = (unsigned short*)p; p += (size_t)NTOK * HD * 2;      // 16.8 MB
  unsigned short* interb = (unsigned short*)p; p += (size_t)NTOK * ID * 2;   // 67 MB
  int* eidx = (int*)p; p += (size_t)NTOK * 4;
  int* perm = (int*)p; p += (size_t)NTOK * 4;
  int* ints = (int*)p;                       // counts[8] | cursors[8] | offs[9]
  int* counts = ints;
  int* cursors = ints + 8;
  int* offs = ints + 16;

  zero_counts_kernel<<<1, 64, 0, stream>>>(counts);
  cast_x_kernel<<<NTOK * HD / 1024, 256, 0, stream>>>(x, xb);
  transpose_cast_kernel<<<dim3(ID / 32, HD / 32, NE), 256, 0, stream>>>(w1, w1t, HD, ID);
  transpose_cast_kernel<<<dim3(HD / 32, ID / 32, 1), 256, 0, stream>>>(wo, wot, ID, HD);
  router_kernel<<<NTOK / 4, 256, 0, stream>>>(x, wr, eidx, counts);
  scan_kernel<<<1, 64, 0, stream>>>(counts, offs);
  scatter_kernel<<<NTOK / 256, 256, 0, stream>>>(eidx, offs, cursors, perm);
  ffn1_kernel<<<dim3(ID / 128, NTOK / 128, NE), 256, 0, stream>>>(
      xb, w1t, b1, perm, offs, counts, interb);
  ffn2_kernel<<<dim3(HD / 128, NTOK / 128), 256, 0, stream>>>(interb, wot, bo, x, out);
  ln_kernel<<<NTOK, 256, 0, stream>>>(out, gamma, beta);
}